// Round 1
// baseline (268.374 us; speedup 1.0000x reference)
//
#include <hip/hip_runtime.h>

// FeatLUT: out[f] = quantize( mean_p( msb[idx_m(p)][f] + lsb[idx_l(p)][f] ) )
// idx = 16*(289*c0 + 17*c1 + c2)  -> only 17^3 = 4913 distinct rows used.
// R2: latency-bound at 36% occupancy (LDS-capped). Pack msb/lsb hists into one
// 32-bit word (lo16/hi16, max count 4096/block) -> LDS 19.7KB -> 32 waves/CU.
// Interleaved 48B compact rows -> 3x dwordx4 + branch-free __mul24 phase B.
// Finalize folded into feat_main (last-block pattern) -> 2 dispatches total.

#define NBINS 4913            // 17^3
#define NPIX  (2048 * 2048)   // 4194304
#define G4    (NPIX / 4)      // 1048576 float4 groups per channel plane
#define NFEAT 20
#define MB    1024            // main grid: 4 blocks/CU
#define MT    512             // threads/block: 8 waves; 4 blocks*8 = 32 waves/CU

// ws layout:
//   cc      @ 0      : 4913 * 12 dwords = 235824 B (48B rows: m0..m4 l0..l4 p p)
//   partial @ 245760 : 1024 * 20 * 4 = 81920 B
//   counter @ 327680 : 4 B

// ---------------------------------------------------------------------------
// Kernel 0: compact used LUT rows (row 16j, j in [0,4913)) into interleaved
// 48-byte rows; also zeroes the completion counter (ws is poisoned each iter).
// Handles both harness layouts (raw int8 bytes vs widened int32): random
// packed bytes essentially never stay in [-32,32) 64x in a row.
// ---------------------------------------------------------------------------
__global__ __launch_bounds__(256) void compact_k(const int* __restrict__ msb,
                                                 const int* __restrict__ lsb,
                                                 int* __restrict__ cc,
                                                 unsigned* __restrict__ counter) {
    if (blockIdx.x == 0 && threadIdx.x == 0) *counter = 0u;

    int ok = 1;
    for (int i = 0; i < 64; ++i) {
        int v = msb[i];
        ok &= (v >= -32 && v < 32);
    }
    const bool is_int32 = (ok != 0);

    const int total = NBINS * 10;                 // 49130 source dwords
    int t = blockIdx.x * 256 + threadIdx.x;       // grid 192*256 = 49152 >= total
    if (t >= total) return;
    int j = t / 10;
    int k = t - j * 10;                           // 0-4: msb dword, 5-9: lsb dword
    const int* base = (k < 5) ? msb : lsb;
    int kk = (k < 5) ? k : k - 5;
    int w;
    if (is_int32) {
        // int per element; row 16j starts at element 16j*20 = 320j
        const int* r = base + j * 320 + kk * 4;
        w = (int)((unsigned)(r[0] & 0xff) | ((unsigned)(r[1] & 0xff) << 8) |
                  ((unsigned)(r[2] & 0xff) << 16) | ((unsigned)(r[3] & 0xff) << 24));
    } else {
        // raw int8; row 16j at byte 320j -> dword 80j, 5 dwords/row
        w = base[j * 80 + kk];
    }
    cc[j * 12 + k] = w;                           // pads (10,11) stay garbage, never read
}

// sign-extend byte lane of packed dword
#define SX(w, sh) ((int)((unsigned)(w) << (sh)) >> 24)
// h <= 4096, byte in [-128,127]: fits v_mad_i32_i24 (full-rate, vs 1/4-rate mul_lo)
#define MACW(h, w, base)                                \
    acc[(base) + 0] += __mul24((h), SX((w), 24));       \
    acc[(base) + 1] += __mul24((h), SX((w), 16));       \
    acc[(base) + 2] += __mul24((h), SX((w), 8));        \
    acc[(base) + 3] += __mul24((h), ((int)(w) >> 24));

__device__ __forceinline__ int wave_red(int v) {
#pragma unroll
    for (int o = 32; o > 0; o >>= 1) v += __shfl_xor(v, o, 64);
    return v;
}

// ---------------------------------------------------------------------------
// Kernel 1: main. MB x MT. Packed hist (msb lo16, lsb hi16; per-block pixel
// count per table = 512*2*4 = 4096 < 2^16, no cross-field carry). Exactly 2
// grid-stride iters, no tail. Per-block partial row, last block finalizes.
// ---------------------------------------------------------------------------
__global__ __launch_bounds__(MT, 8) void feat_main(const float* __restrict__ xin,
                                                   const float* __restrict__ xs,
                                                   const int* __restrict__ cc,
                                                   int* __restrict__ partial,
                                                   unsigned* __restrict__ counter,
                                                   float* __restrict__ out) {
    __shared__ int hist[NBINS];                 // 19652 B
    __shared__ int wsum[MT / 64][NFEAT];        // 640 B
    __shared__ unsigned last_s;

    for (int i = threadIdx.x; i < NBINS; i += MT) hist[i] = 0;
    __syncthreads();

    const float4* a = (const float4*)xin;
    const float4* b = (const float4*)xs;
    int g = blockIdx.x * MT + threadIdx.x;
#pragma unroll
    for (int it = 0; it < 2; ++it) {
        float4 a0 = a[g], a1 = a[g + G4], a2 = a[g + 2 * G4];
        float4 b0 = b[g], b1 = b[g + G4], b2 = b[g + 2 * G4];

        int m0 = (int)fmaf(a0.x, 289.0f, fmaf(a1.x, 17.0f, a2.x));
        int m1 = (int)fmaf(a0.y, 289.0f, fmaf(a1.y, 17.0f, a2.y));
        int m2 = (int)fmaf(a0.z, 289.0f, fmaf(a1.z, 17.0f, a2.z));
        int m3 = (int)fmaf(a0.w, 289.0f, fmaf(a1.w, 17.0f, a2.w));
        int s0 = (int)fmaf(b0.x, 289.0f, fmaf(b1.x, 17.0f, b2.x));
        int s1 = (int)fmaf(b0.y, 289.0f, fmaf(b1.y, 17.0f, b2.y));
        int s2 = (int)fmaf(b0.z, 289.0f, fmaf(b1.z, 17.0f, b2.z));
        int s3 = (int)fmaf(b0.w, 289.0f, fmaf(b1.w, 17.0f, b2.w));

        atomicAdd(&hist[m0], 1);
        atomicAdd(&hist[m1], 1);
        atomicAdd(&hist[m2], 1);
        atomicAdd(&hist[m3], 1);
        atomicAdd(&hist[s0], 1 << 16);
        atomicAdd(&hist[s1], 1 << 16);
        atomicAdd(&hist[s2], 1 << 16);
        atomicAdd(&hist[s3], 1 << 16);
        g += MB * MT;                           // MB*MT*2 == G4 exactly
    }
    __syncthreads();

    // per-block dot: acc[f] += hm[j]*msb_row[j][f] + hl[j]*lsb_row[j][f]
    // branch-free (P(bin empty) ~3.5% with combined hist), straight-line loop.
    int acc[NFEAT];
#pragma unroll
    for (int f = 0; f < NFEAT; ++f) acc[f] = 0;

    for (int j = threadIdx.x; j < NBINS; j += MT) {   // 9-10 iters
        int h = hist[j];                               // consecutive j: 2-way LDS, free
        int hm = h & 0xffff;
        int hl = (int)((unsigned)h >> 16);
        const int4* r = (const int4*)(cc + j * 12);    // 48B row, 16B-aligned
        int4 q0 = r[0], q1 = r[1], q2 = r[2];
        MACW(hm, q0.x, 0)  MACW(hm, q0.y, 4)  MACW(hm, q0.z, 8)
        MACW(hm, q0.w, 12) MACW(hm, q1.x, 16)
        MACW(hl, q1.y, 0)  MACW(hl, q1.z, 4)  MACW(hl, q1.w, 8)
        MACW(hl, q2.x, 12) MACW(hl, q2.y, 16)
    }

    // wave butterfly -> per-wave LDS row -> thread f sums 8 -> per-block partial
    const int lane = threadIdx.x & 63;
    const int wv = threadIdx.x >> 6;
#pragma unroll
    for (int f = 0; f < NFEAT; ++f) {
        int v = wave_red(acc[f]);
        if (lane == 0) wsum[wv][f] = v;
    }
    __syncthreads();
    if (threadIdx.x < NFEAT) {
        int s = 0;
#pragma unroll
        for (int w = 0; w < MT / 64; ++w) s += wsum[w][threadIdx.x];
        partial[blockIdx.x * NFEAT + threadIdx.x] = s;
    }

    // last-block finalize (fence + device-scope counter; no spin -> no
    // co-residency assumption). compact_k zeroed counter this iteration.
    __threadfence();
    __syncthreads();
    if (threadIdx.x == 0) last_s = atomicAdd(counter, 1u);
    __syncthreads();
    if (last_s != MB - 1) return;

    __threadfence();  // acquire: see all blocks' partial rows
    int accf[NFEAT];
    const int* p0 = partial + threadIdx.x * NFEAT;          // rows t and t+512
    const int* p1 = partial + (threadIdx.x + MT) * NFEAT;   // coalesced dwordx4
#pragma unroll
    for (int f = 0; f < NFEAT; ++f) accf[f] = p0[f] + p1[f];

#pragma unroll
    for (int f = 0; f < NFEAT; ++f) {
        int v = wave_red(accf[f]);
        if (lane == 0) wsum[wv][f] = v;
    }
    __syncthreads();
    if (threadIdx.x < NFEAT) {
        int s = 0;
#pragma unroll
        for (int w = 0; w < MT / 64; ++w) s += wsum[w][threadIdx.x];
        // mean*4 = S / 2^20 exactly; RNE rint == jnp.round
        double m4 = (double)s * (1.0 / 1048576.0);
        double r = rint(m4);
        float v = (float)(r * 0.25);
        v = fminf(fmaxf(v, -32.0f), 31.75f);
        out[threadIdx.x] = v;
    }
}

extern "C" void kernel_launch(void* const* d_in, const int* in_sizes, int n_in,
                              void* d_out, int out_size, void* d_ws, size_t ws_size,
                              hipStream_t stream) {
    const float* xin = (const float*)d_in[0];
    const float* xs = (const float*)d_in[1];
    const int* msb = (const int*)d_in[2];
    const int* lsb = (const int*)d_in[3];
    float* out = (float*)d_out;

    int* cc = (int*)d_ws;
    int* partial = (int*)((char*)d_ws + 245760);
    unsigned* counter = (unsigned*)((char*)d_ws + 327680);

    compact_k<<<192, 256, 0, stream>>>(msb, lsb, cc, counter);
    feat_main<<<MB, MT, 0, stream>>>(xin, xs, cc, partial, counter, out);
}